// Round 4
// baseline (989.778 us; speedup 1.0000x reference)
//
#include <hip/hip_runtime.h>
#include <stdint.h>

#define CA 64     // in channels
#define CB 128    // out channels
#define KOFF 27   // 3^3 offsets
#define BN_EPS 1e-4f

typedef short bf16x8 __attribute__((ext_vector_type(8)));
typedef float f32x4 __attribute__((ext_vector_type(4)));
typedef unsigned int u32x4 __attribute__((ext_vector_type(4)));
typedef unsigned short u16x4 __attribute__((ext_vector_type(4)));

__device__ __forceinline__ unsigned short f2bf(float f) {
  union { float f; uint32_t u; } c; c.f = f;
  uint32_t u = c.u;
  return (unsigned short)((u + 0x7FFFu + ((u >> 16) & 1u)) >> 16);  // RNE
}

// ---- mask dtype detection: if int32 layout, bytes at i%4!=0 are all zero ----
__global__ void detect_mask_k(const unsigned char* __restrict__ m, int* flag) {
  unsigned v = 0;
  for (int i = threadIdx.x; i < 4096; i += 256)
    if (i & 3) v |= m[i];
  if (v) atomicOr(flag, 1);   // 1 => byte/bool layout, 0 => int32 layout
}

// ---- transposed merged neighbor+mask: nt[k][i] = mask[i][k] ? nbr[i][k] : n ----
// coalesced writes; reads strided but single-pass
__global__ void make_nbrt_k(const int* __restrict__ nbr, const void* __restrict__ mp,
                            const int* __restrict__ flag, int* __restrict__ nt, int n) {
  int j = blockIdx.x * blockDim.x + threadIdx.x;
  if (j >= n * KOFF) return;
  int k = j / n, row = j - k * n;
  int src = row * KOFF + k;
  bool m = (*flag) ? (((const unsigned char*)mp)[src] != 0)
                   : (((const int*)mp)[src] != 0);
  nt[j] = m ? nbr[src] : n;
}

// ---- zero rows at index n of the bf16 feature buffers ----
__global__ void zero_rows_k(unsigned short* hb1, unsigned short* fb,
                            unsigned short* hb2, int n) {
  int i = threadIdx.x;
  if (i < CA) { hb1[(size_t)n * CA + i] = 0; fb[(size_t)n * CA + i] = 0; }
  if (i < CB) { hb2[(size_t)n * CB + i] = 0; }
}

// ---- all weight transposes + bf16 convert: wt[k][co][ci] = bf16(w[k][ci][co]) ----
__global__ void transpose_all_k(const float* __restrict__ W1, const float* __restrict__ W2,
                                const float* __restrict__ Wnin,
                                unsigned short* __restrict__ w1t, unsigned short* __restrict__ w2t,
                                unsigned short* __restrict__ wnt) {
  const int t1 = KOFF * CA * CB, t2 = KOFF * CB * CB, t3 = CA * CB;
  int idx = blockIdx.x * blockDim.x + threadIdx.x;
  if (idx < t1) {
    int ci = idx % CA; int r = idx / CA; int co = r % CB; int k = r / CB;
    w1t[idx] = f2bf(W1[((size_t)k * CA + ci) * CB + co]);
  } else if (idx < t1 + t2) {
    int j = idx - t1;
    int ci = j % CB; int r = j / CB; int co = r % CB; int k = r / CB;
    w2t[j] = f2bf(W2[((size_t)k * CB + ci) * CB + co]);
  } else if (idx < t1 + t2 + t3) {
    int j = idx - t1 - t2;
    int ci = j % CA; int co = j / CA;
    wnt[j] = f2bf(Wnin[(size_t)ci * CB + co]);
  }
}

// ---- per-channel sum & sumsq (training-mode BN stats) ----
template<int C>
__global__ void col_stats_k(const float* __restrict__ x, int n, float* __restrict__ sums) {
  __shared__ float ssum[C], ssq[C];
  int t = threadIdx.x;
  for (int i = t; i < C; i += 256) { ssum[i] = 0.f; ssq[i] = 0.f; }
  __syncthreads();
  const int c = t % C;
  const int rpb = 256 / C;
  float s = 0.f, q = 0.f;
  for (int r = blockIdx.x * rpb + t / C; r < n; r += gridDim.x * rpb) {
    float v = x[(size_t)r * C + c];
    s += v; q += v * v;
  }
  atomicAdd(&ssum[c], s);
  atomicAdd(&ssq[c], q);
  __syncthreads();
  for (int i = t; i < C; i += 256) {
    atomicAdd(&sums[i], ssum[i]);
    atomicAdd(&sums[C + i], ssq[i]);
  }
}

template<int C>
__global__ void bn_finalize_k(const float* __restrict__ sums, const float* __restrict__ gamma,
                              const float* __restrict__ beta, float* __restrict__ sc, int n) {
  int c = threadIdx.x;
  if (c >= C) return;
  float inv_n = 1.f / (float)n;
  float mean = sums[c] * inv_n;
  float var = sums[C + c] * inv_n - mean * mean;
  float rstd = rsqrtf(var + BN_EPS);
  float scale = gamma[c] * rstd;
  sc[c] = scale;
  sc[C + c] = beta[c] - mean * scale;
}

template<int C, bool RAW>
__global__ void bn_apply_k(const float* __restrict__ x, const float* __restrict__ sc,
                           unsigned short* __restrict__ h, unsigned short* __restrict__ raw,
                           int total) {
  int idx = (blockIdx.x * blockDim.x + threadIdx.x) * 4;
  if (idx >= total) return;
  f32x4 v = *(const f32x4*)&x[idx];
  int c0 = idx % C;
  u16x4 ho, ro;
#pragma unroll
  for (int j = 0; j < 4; j++) {
    float s = sc[c0 + j], b = sc[C + c0 + j];
    float hv = fmaxf(v[j] * s + b, 0.f);
    ho[j] = f2bf(hv);
    if (RAW) ro[j] = f2bf(v[j]);
  }
  *(u16x4*)&h[idx] = ho;
  if (RAW) *(u16x4*)&raw[idx] = ro;
}

// ---- barrier-free direct-gather MFMA subconv ----
// Each wave owns 32 rows x 128 cols; A-fragments load DIRECTLY from global
// (lane l16 = row, quad = 16B channel chunk) -> no LDS, no __syncthreads, no
// barrier drain. Register pipeline: nbr ring-3, A ring-3 (issue k+2 at iter k),
// B double-buffer (one ks-step ahead). Unroll x3 folds ring indices.
template<int CIN, bool FUSE>
__launch_bounds__(256, 2)
__global__ void conv_k(const unsigned short* __restrict__ hin,
                       const unsigned short* __restrict__ wt,
                       const int* __restrict__ nbrt,    // [KOFF][n]
                       const unsigned short* __restrict__ fbraw,
                       const unsigned short* __restrict__ wnt,
                       float* __restrict__ out, int n) {
  constexpr int NKS = CIN / 32;     // MFMA K-steps per offset
  const int t = threadIdx.x;
  const int lane = t & 63;
  const int wave = t >> 6;
  const int l16 = lane & 15;
  const int quad = lane >> 4;
  const int row0 = blockIdx.x * 128 + wave * 32;
  const int r0 = row0 + l16;        // rt=0 row for this lane
  const int r1 = row0 + 16 + l16;   // rt=1 row

  f32x4 acc[2][8];
#pragma unroll
  for (int rt = 0; rt < 2; rt++)
#pragma unroll
    for (int ct = 0; ct < 8; ct++) acc[rt][ct] = f32x4{0, 0, 0, 0};

  int nbrv[3][2];
  bf16x8 A[3][2][NKS];
  bf16x8 Bb[2][8];

#define LDNBR(K, S) do { \
    nbrv[S][0] = (r0 < n) ? nbrt[(size_t)(K) * n + r0] : n; \
    nbrv[S][1] = (r1 < n) ? nbrt[(size_t)(K) * n + r1] : n; } while (0)

#define LDA(S) do { \
    _Pragma("unroll") \
    for (int _rt = 0; _rt < 2; _rt++) { \
      const unsigned short* _rp = hin + (size_t)nbrv[S][_rt] * CIN + quad * 8; \
      _Pragma("unroll") \
      for (int _ks = 0; _ks < NKS; _ks++) A[S][_rt][_ks] = *(const bf16x8*)(_rp + _ks * 32); \
    } } while (0)

#define LDB(K, KS, BUF) do { \
    const unsigned short* _wp = wt + ((size_t)(K) * CB + l16) * CIN + (KS) * 32 + quad * 8; \
    _Pragma("unroll") \
    for (int _ct = 0; _ct < 8; _ct++) Bb[BUF][_ct] = *(const bf16x8*)(_wp + _ct * 16 * CIN); \
  } while (0)

  if constexpr (FUSE) {
    // NiN shortcut: acc += fb(rows) @ wnt (K = CA), sequential-coalesced loads
    int rr0 = (r0 < n) ? r0 : n;
    int rr1 = (r1 < n) ? r1 : n;
#pragma unroll
    for (int ks = 0; ks < CA / 32; ks++) {
      bf16x8 a0 = *(const bf16x8*)&fbraw[(size_t)rr0 * CA + ks * 32 + quad * 8];
      bf16x8 a1 = *(const bf16x8*)&fbraw[(size_t)rr1 * CA + ks * 32 + quad * 8];
#pragma unroll
      for (int ct = 0; ct < 8; ct++) {
        bf16x8 b = *(const bf16x8*)&wnt[((size_t)(ct * 16 + l16)) * CA + ks * 32 + quad * 8];
        acc[0][ct] = __builtin_amdgcn_mfma_f32_16x16x32_bf16(a0, b, acc[0][ct], 0, 0, 0);
        acc[1][ct] = __builtin_amdgcn_mfma_f32_16x16x32_bf16(a1, b, acc[1][ct], 0, 0, 0);
      }
    }
  }

  // ---- pipeline prologue ----
  LDNBR(0, 0); LDNBR(1, 1); LDNBR(2, 2);
  LDA(0); LDA(1);
  LDB(0, 0, 0);

  // ---- main loop: 9 x (unroll 3); ring indices d, (d+2)%3 fold statically ----
  for (int kk = 0; kk < KOFF / 3; kk++) {
#pragma unroll
    for (int d = 0; d < 3; d++) {
      const int k = kk * 3 + d;
      if (k + 3 < KOFF) LDNBR(k + 3, d);   // nbrv[d] consumed by LDA 2 iters ago
#pragma unroll
      for (int ks = 0; ks < NKS; ks++) {
        if (ks + 1 < NKS) LDB(k, ks + 1, (ks + 1) & 1);
        else if (k + 1 < KOFF) LDB(k + 1, 0, 0);
        if (ks == 0 && k + 2 < KOFF) LDA((d + 2) % 3);  // gather offset k+2
#pragma unroll
        for (int ct = 0; ct < 8; ct++) {
          acc[0][ct] = __builtin_amdgcn_mfma_f32_16x16x32_bf16(A[d][0][ks], Bb[ks & 1][ct], acc[0][ct], 0, 0, 0);
          acc[1][ct] = __builtin_amdgcn_mfma_f32_16x16x32_bf16(A[d][1][ks], Bb[ks & 1][ct], acc[1][ct], 0, 0, 0);
        }
      }
    }
  }
#undef LDNBR
#undef LDA
#undef LDB

  // epilogue: C/D layout col=lane&15, row=(lane>>4)*4+reg
#pragma unroll
  for (int rt = 0; rt < 2; rt++)
#pragma unroll
    for (int ct = 0; ct < 8; ct++)
#pragma unroll
      for (int i = 0; i < 4; i++) {
        int r = row0 + rt * 16 + quad * 4 + i;
        if (r < n) out[(size_t)r * CB + ct * 16 + l16] = acc[rt][ct][i];
      }
}

extern "C" void kernel_launch(void* const* d_in, const int* in_sizes, int n_in,
                              void* d_out, int out_size, void* d_ws, size_t ws_size,
                              hipStream_t stream) {
  const float* feat   = (const float*)d_in[0];
  const float* gamma1 = (const float*)d_in[1];
  const float* beta1  = (const float*)d_in[2];
  const float* W1     = (const float*)d_in[3];
  const float* gamma2 = (const float*)d_in[4];
  const float* beta2  = (const float*)d_in[5];
  const float* W2     = (const float*)d_in[6];
  const float* Wnin   = (const float*)d_in[7];
  const int*   nbr    = (const int*)d_in[8];
  const void*  mask   = d_in[9];
  float* out = (float*)d_out;

  const int n = in_sizes[0] / CA;  // 100000

  char* ws = (char*)d_ws;
  size_t off = 0;
  auto alloc = [&](size_t bytes) { size_t p = off; off += (bytes + 255) & ~(size_t)255; return p; };
  int*            flag  = (int*)           (ws + alloc(256));
  float*          sums1 = (float*)         (ws + alloc(2 * CA * 4));
  float*          sums2 = (float*)         (ws + alloc(2 * CB * 4));
  float*          sc1   = (float*)         (ws + alloc(2 * CA * 4));
  float*          sc2   = (float*)         (ws + alloc(2 * CB * 4));
  int*            nbrt  = (int*)           (ws + alloc((size_t)n * KOFF * 4));
  unsigned short* fb    = (unsigned short*)(ws + alloc((size_t)(n + 1) * CA * 2));
  unsigned short* hb1   = (unsigned short*)(ws + alloc((size_t)(n + 1) * CA * 2));
  float*          out1  = (float*)         (ws + alloc((size_t)n * CB * 4));
  unsigned short* hb2   = (unsigned short*)(ws + alloc((size_t)(n + 1) * CB * 2));
  unsigned short* w1t   = (unsigned short*)(ws + alloc((size_t)KOFF * CB * CA * 2));
  unsigned short* w2t   = (unsigned short*)(ws + alloc((size_t)KOFF * CB * CB * 2));
  unsigned short* wnt   = (unsigned short*)(ws + alloc((size_t)CB * CA * 2));

  // zero flag + stats accumulators (ws is poisoned 0xAA before every launch)
  hipMemsetAsync(d_ws, 0, 1792, stream);

  detect_mask_k<<<1, 256, 0, stream>>>((const unsigned char*)mask, flag);
  make_nbrt_k<<<(n * KOFF + 255) / 256, 256, 0, stream>>>(nbr, mask, flag, nbrt, n);
  zero_rows_k<<<1, 256, 0, stream>>>(hb1, fb, hb2, n);

  {
    int tot = KOFF * CA * CB + KOFF * CB * CB + CA * CB;
    transpose_all_k<<<(tot + 255) / 256, 256, 0, stream>>>(W1, W2, Wnin, w1t, w2t, wnt);
  }

  // stage 1: BN stats -> scale/shift -> h1 (bn+relu bf16) + raw feat bf16
  col_stats_k<CA><<<256, 256, 0, stream>>>(feat, n, sums1);
  bn_finalize_k<CA><<<1, CA, 0, stream>>>(sums1, gamma1, beta1, sc1, n);
  bn_apply_k<CA, true><<<(n * CA / 4 + 255) / 256, 256, 0, stream>>>(feat, sc1, hb1, fb, n * CA);

  // conv1: out1 = subconv(h1, W1)  [N,128] fp32
  conv_k<CA, false><<<(n + 127) / 128, 256, 0, stream>>>(hb1, w1t, nbrt, nullptr, nullptr, out1, n);

  // stage 2
  col_stats_k<CB><<<256, 256, 0, stream>>>(out1, n, sums2);
  bn_finalize_k<CB><<<1, CB, 0, stream>>>(sums2, gamma2, beta2, sc2, n);
  bn_apply_k<CB, false><<<(n * CB / 4 + 255) / 256, 256, 0, stream>>>(out1, sc2, hb2, nullptr, n * CB);

  // conv2 + fused NiN shortcut
  conv_k<CB, true><<<(n + 127) / 128, 256, 0, stream>>>(hb2, w2t, nbrt, fb, wnt, out, n);
}

// Round 5
// 624.892 us; speedup vs baseline: 1.5839x; 1.5839x over previous
//
#include <hip/hip_runtime.h>
#include <stdint.h>

#define CA 64     // in channels
#define CB 128    // out channels
#define KOFF 27   // 3^3 offsets
#define BN_EPS 1e-4f

typedef short bf16x8 __attribute__((ext_vector_type(8)));
typedef float f32x4 __attribute__((ext_vector_type(4)));
typedef unsigned int u32x4 __attribute__((ext_vector_type(4)));
typedef unsigned short u16x4 __attribute__((ext_vector_type(4)));

__device__ __forceinline__ unsigned short f2bf(float f) {
  union { float f; uint32_t u; } c; c.f = f;
  uint32_t u = c.u;
  return (unsigned short)((u + 0x7FFFu + ((u >> 16) & 1u)) >> 16);  // RNE
}

// LDS-only barrier (CK block_sync_lds pattern). The design does NOT depend on
// global loads staying in flight across it — each phase's gathers are waited
// and committed before this barrier.
__device__ __forceinline__ void barrier_lds() {
  asm volatile("s_waitcnt lgkmcnt(0)\n\ts_barrier" ::: "memory");
}

// ---- mask dtype detection: if int32 layout, bytes at i%4!=0 are all zero ----
__global__ void detect_mask_k(const unsigned char* __restrict__ m, int* flag) {
  unsigned v = 0;
  for (int i = threadIdx.x; i < 4096; i += 256)
    if (i & 3) v |= m[i];
  if (v) atomicOr(flag, 1);   // 1 => byte/bool layout, 0 => int32 layout
}

// ---- transposed merged neighbor+mask: nt[k][i] = mask[i][k] ? nbr[i][k] : n ----
__global__ void make_nbrt_k(const int* __restrict__ nbr, const void* __restrict__ mp,
                            const int* __restrict__ flag, int* __restrict__ nt, int n) {
  int j = blockIdx.x * blockDim.x + threadIdx.x;
  if (j >= n * KOFF) return;
  int k = j / n, row = j - k * n;
  int src = row * KOFF + k;
  bool m = (*flag) ? (((const unsigned char*)mp)[src] != 0)
                   : (((const int*)mp)[src] != 0);
  nt[j] = m ? nbr[src] : n;
}

// ---- zero rows at index n of the bf16 feature buffers ----
__global__ void zero_rows_k(unsigned short* hb1, unsigned short* fb,
                            unsigned short* hb2, int n) {
  int i = threadIdx.x;
  if (i < CA) { hb1[(size_t)n * CA + i] = 0; fb[(size_t)n * CA + i] = 0; }
  if (i < CB) { hb2[(size_t)n * CB + i] = 0; }
}

// ---- all weight transposes + bf16 convert: wt[k][co][ci] = bf16(w[k][ci][co]) ----
__global__ void transpose_all_k(const float* __restrict__ W1, const float* __restrict__ W2,
                                const float* __restrict__ Wnin,
                                unsigned short* __restrict__ w1t, unsigned short* __restrict__ w2t,
                                unsigned short* __restrict__ wnt) {
  const int t1 = KOFF * CA * CB, t2 = KOFF * CB * CB, t3 = CA * CB;
  int idx = blockIdx.x * blockDim.x + threadIdx.x;
  if (idx < t1) {
    int ci = idx % CA; int r = idx / CA; int co = r % CB; int k = r / CB;
    w1t[idx] = f2bf(W1[((size_t)k * CA + ci) * CB + co]);
  } else if (idx < t1 + t2) {
    int j = idx - t1;
    int ci = j % CB; int r = j / CB; int co = r % CB; int k = r / CB;
    w2t[j] = f2bf(W2[((size_t)k * CB + ci) * CB + co]);
  } else if (idx < t1 + t2 + t3) {
    int j = idx - t1 - t2;
    int ci = j % CA; int co = j / CA;
    wnt[j] = f2bf(Wnin[(size_t)ci * CB + co]);
  }
}

// ---- per-channel sum & sumsq (training-mode BN stats) ----
template<int C>
__global__ void col_stats_k(const float* __restrict__ x, int n, float* __restrict__ sums) {
  __shared__ float ssum[C], ssq[C];
  int t = threadIdx.x;
  for (int i = t; i < C; i += 256) { ssum[i] = 0.f; ssq[i] = 0.f; }
  __syncthreads();
  const int c = t % C;
  const int rpb = 256 / C;
  float s = 0.f, q = 0.f;
  for (int r = blockIdx.x * rpb + t / C; r < n; r += gridDim.x * rpb) {
    float v = x[(size_t)r * C + c];
    s += v; q += v * v;
  }
  atomicAdd(&ssum[c], s);
  atomicAdd(&ssq[c], q);
  __syncthreads();
  for (int i = t; i < C; i += 256) {
    atomicAdd(&sums[i], ssum[i]);
    atomicAdd(&sums[C + i], ssq[i]);
  }
}

template<int C>
__global__ void bn_finalize_k(const float* __restrict__ sums, const float* __restrict__ gamma,
                              const float* __restrict__ beta, float* __restrict__ sc, int n) {
  int c = threadIdx.x;
  if (c >= C) return;
  float inv_n = 1.f / (float)n;
  float mean = sums[c] * inv_n;
  float var = sums[C + c] * inv_n - mean * mean;
  float rstd = rsqrtf(var + BN_EPS);
  float scale = gamma[c] * rstd;
  sc[c] = scale;
  sc[C + c] = beta[c] - mean * scale;
}

template<int C, bool RAW>
__global__ void bn_apply_k(const float* __restrict__ x, const float* __restrict__ sc,
                           unsigned short* __restrict__ h, unsigned short* __restrict__ raw,
                           int total) {
  int idx = (blockIdx.x * blockDim.x + threadIdx.x) * 4;
  if (idx >= total) return;
  f32x4 v = *(const f32x4*)&x[idx];
  int c0 = idx % C;
  u16x4 ho, ro;
#pragma unroll
  for (int j = 0; j < 4; j++) {
    float s = sc[c0 + j], b = sc[C + c0 + j];
    float hv = fmaxf(v[j] * s + b, 0.f);
    ho[j] = f2bf(hv);
    if (RAW) ro[j] = f2bf(v[j]);
  }
  *(u16x4*)&h[idx] = ho;
  if (RAW) *(u16x4*)&raw[idx] = ro;
}

// ---- phase-staged gather-GEMM subconv ----
// out[n,:] = sum_k hin[nbrt[k][n],:] @ W[k]   (+ FUSE: fb(rows) @ wnt)
// Block 64 rows x 128 cols, 256 threads (4 waves of 64x32). Offsets processed
// in pairs (G=2): per phase, ALL gathers for the pair are issued back-to-back
// (structurally in flight — nothing intervenes), next phase's indices load,
// then the full 2-offset MFMA section runs on the previous pair's LDS buffer,
// then gathers are waited+committed, one LDS barrier. 14 barriers vs 27.
// LDS: conv2 69.6KB -> 2 blocks/CU; conv1 36.9KB -> 4 blocks/CU.
template<int CIN, bool FUSE>
__launch_bounds__(256)
__global__ void conv_k(const unsigned short* __restrict__ hin,
                       const unsigned short* __restrict__ wt,
                       const int* __restrict__ nbrt,    // [KOFF][n]
                       const unsigned short* __restrict__ fbraw,
                       const unsigned short* __restrict__ wnt,
                       float* __restrict__ out, int n) {
  constexpr int TR  = 64;
  constexpr int STR = CIN + 8;        // +16B pad (r1-r3 measured ~8% conflict, ok)
  constexpr int NKS = CIN / 32;       // MFMA K-steps per offset (2 or 4)
  constexpr int CH  = CIN / 8;        // 16B chunks per row (8 or 16)
  constexpr int RPP = 256 / CH;       // rows staged per pass (32 or 16)
  constexpr int NP  = TR / RPP;       // passes per offset (2 or 4)
  constexpr int G   = 2;              // offsets per phase
  constexpr int NPH = (KOFF + G - 1) / G;  // 14 (last phase: 1 offset)
  constexpr int GB  = G * NP;         // gather chunks per thread per phase (4/8)

  __shared__ alignas(16) unsigned short buf[2][G][TR * STR];

  const int t = threadIdx.x;
  const int rowbase = blockIdx.x * TR;
  const int lane = t & 63, wave = t >> 6, l16 = lane & 15, quad = lane >> 4;
  const int colbase = wave * 32;
  const int goff = (t % CH) * 8;      // 16B chunk offset within row (shorts)
  const int grow = t / CH;            // row within a staging pass
  const int boff0 = (colbase + l16) * CIN + quad * 8;
  const int boff1 = boff0 + 16 * CIN;

  f32x4 acc[4][2];
#pragma unroll
  for (int i = 0; i < 4; i++) { acc[i][0] = f32x4{0,0,0,0}; acc[i][1] = f32x4{0,0,0,0}; }

  int ir[GB];
  u32x4 gv[GB];

#define LOADIDX(P) do { \
    _Pragma("unroll") \
    for (int j = 0; j < GB; j++) { \
      int k = (P) * G + j / NP; \
      int r = rowbase + (j % NP) * RPP + grow; \
      ir[j] = (k < KOFF && r < n) ? nbrt[(size_t)k * n + r] : n; \
    } } while (0)

#define GATHER() do { \
    _Pragma("unroll") \
    for (int j = 0; j < GB; j++) \
      gv[j] = *(const u32x4*)&hin[(size_t)ir[j] * CIN + goff]; } while (0)

#define COMMIT(PAR) do { \
    _Pragma("unroll") \
    for (int j = 0; j < GB; j++) \
      *(u32x4*)&buf[PAR][j / NP][((j % NP) * RPP + grow) * STR + goff] = gv[j]; } while (0)

#define MFMA_PHASE(PAR, K0, GCNT) do { \
    _Pragma("unroll") \
    for (int g = 0; g < (GCNT); g++) { \
      const unsigned short* wk = wt + (size_t)((K0) + g) * CB * CIN; \
      const unsigned short* bp = &buf[PAR][g][0]; \
      _Pragma("unroll") \
      for (int ks = 0; ks < NKS; ks++) { \
        bf16x8 b0 = *(const bf16x8*)&wk[boff0 + ks * 32]; \
        bf16x8 b1 = *(const bf16x8*)&wk[boff1 + ks * 32]; \
        _Pragma("unroll") \
        for (int rt = 0; rt < 4; rt++) { \
          bf16x8 a = *(const bf16x8*)&bp[(rt * 16 + l16) * STR + ks * 32 + quad * 8]; \
          acc[rt][0] = __builtin_amdgcn_mfma_f32_16x16x32_bf16(a, b0, acc[rt][0], 0, 0, 0); \
          acc[rt][1] = __builtin_amdgcn_mfma_f32_16x16x32_bf16(a, b1, acc[rt][1], 0, 0, 0); \
        } \
      } \
    } } while (0)

  // ---- prologue: phase 0 gathers in flight under the NiN MFMA ----
  LOADIDX(0);
  GATHER();
  LOADIDX(1);

  if constexpr (FUSE) {
    // NiN shortcut: acc += fb(rows) @ wnt (K = CA); coalesced direct loads
    int rr[4];
#pragma unroll
    for (int rt = 0; rt < 4; rt++) {
      int g = rowbase + rt * 16 + l16;
      rr[rt] = (g < n) ? g : n;
    }
#pragma unroll
    for (int ks = 0; ks < CA / 32; ks++) {
      bf16x8 b0 = *(const bf16x8*)&wnt[(colbase + l16) * CA + ks * 32 + quad * 8];
      bf16x8 b1 = *(const bf16x8*)&wnt[(colbase + 16 + l16) * CA + ks * 32 + quad * 8];
#pragma unroll
      for (int rt = 0; rt < 4; rt++) {
        bf16x8 a = *(const bf16x8*)&fbraw[(size_t)rr[rt] * CA + ks * 32 + quad * 8];
        acc[rt][0] = __builtin_amdgcn_mfma_f32_16x16x32_bf16(a, b0, acc[rt][0], 0, 0, 0);
        acc[rt][1] = __builtin_amdgcn_mfma_f32_16x16x32_bf16(a, b1, acc[rt][1], 0, 0, 0);
      }
    }
  }

  COMMIT(0);
  barrier_lds();

  // ---- main phases: MFMA(p-1 data) overlaps phase-p gathers ----
#pragma unroll
  for (int p = 1; p < NPH; p++) {
    GATHER();                       // gathers for phase p (ir loaded last phase)
    LOADIDX(p + 1);                 // indices for p+1 (k>=KOFF -> zero row)
    MFMA_PHASE((p - 1) & 1, (p - 1) * G, G);
    COMMIT(p & 1);
    barrier_lds();
  }

  // final phase's data: offset 26 only (g=0 of buf[(NPH-1)&1])
  MFMA_PHASE((NPH - 1) & 1, (NPH - 1) * G, 1);

#undef LOADIDX
#undef GATHER
#undef COMMIT
#undef MFMA_PHASE

  // epilogue: C/D layout col=lane&15, row=(lane>>4)*4+reg
#pragma unroll
  for (int rt = 0; rt < 4; rt++)
#pragma unroll
    for (int ct = 0; ct < 2; ct++)
#pragma unroll
      for (int i = 0; i < 4; i++) {
        int r = rowbase + rt * 16 + quad * 4 + i;
        if (r < n) out[(size_t)r * CB + colbase + ct * 16 + l16] = acc[rt][ct][i];
      }
}

extern "C" void kernel_launch(void* const* d_in, const int* in_sizes, int n_in,
                              void* d_out, int out_size, void* d_ws, size_t ws_size,
                              hipStream_t stream) {
  const float* feat   = (const float*)d_in[0];
  const float* gamma1 = (const float*)d_in[1];
  const float* beta1  = (const float*)d_in[2];
  const float* W1     = (const float*)d_in[3];
  const float* gamma2 = (const float*)d_in[4];
  const float* beta2  = (const float*)d_in[5];
  const float* W2     = (const float*)d_in[6];
  const float* Wnin   = (const float*)d_in[7];
  const int*   nbr    = (const int*)d_in[8];
  const void*  mask   = d_in[9];
  float* out = (float*)d_out;

  const int n = in_sizes[0] / CA;  // 100000

  char* ws = (char*)d_ws;
  size_t off = 0;
  auto alloc = [&](size_t bytes) { size_t p = off; off += (bytes + 255) & ~(size_t)255; return p; };
  int*            flag  = (int*)           (ws + alloc(256));
  float*          sums1 = (float*)         (ws + alloc(2 * CA * 4));
  float*          sums2 = (float*)         (ws + alloc(2 * CB * 4));
  float*          sc1   = (float*)         (ws + alloc(2 * CA * 4));
  float*          sc2   = (float*)         (ws + alloc(2 * CB * 4));
  int*            nbrt  = (int*)           (ws + alloc((size_t)n * KOFF * 4));
  unsigned short* fb    = (unsigned short*)(ws + alloc((size_t)(n + 1) * CA * 2));
  unsigned short* hb1   = (unsigned short*)(ws + alloc((size_t)(n + 1) * CA * 2));
  float*          out1  = (float*)         (ws + alloc((size_t)n * CB * 4));
  unsigned short* hb2   = (unsigned short*)(ws + alloc((size_t)(n + 1) * CB * 2));
  unsigned short* w1t   = (unsigned short*)(ws + alloc((size_t)KOFF * CB * CA * 2));
  unsigned short* w2t   = (unsigned short*)(ws + alloc((size_t)KOFF * CB * CB * 2));
  unsigned short* wnt   = (unsigned short*)(ws + alloc((size_t)CB * CA * 2));

  // zero flag + stats accumulators (ws is poisoned 0xAA before every launch)
  hipMemsetAsync(d_ws, 0, 1792, stream);

  detect_mask_k<<<1, 256, 0, stream>>>((const unsigned char*)mask, flag);
  make_nbrt_k<<<(n * KOFF + 255) / 256, 256, 0, stream>>>(nbr, mask, flag, nbrt, n);
  zero_rows_k<<<1, 256, 0, stream>>>(hb1, fb, hb2, n);

  {
    int tot = KOFF * CA * CB + KOFF * CB * CB + CA * CB;
    transpose_all_k<<<(tot + 255) / 256, 256, 0, stream>>>(W1, W2, Wnin, w1t, w2t, wnt);
  }

  // stage 1: BN stats -> scale/shift -> h1 (bn+relu bf16) + raw feat bf16
  col_stats_k<CA><<<256, 256, 0, stream>>>(feat, n, sums1);
  bn_finalize_k<CA><<<1, CA, 0, stream>>>(sums1, gamma1, beta1, sc1, n);
  bn_apply_k<CA, true><<<(n * CA / 4 + 255) / 256, 256, 0, stream>>>(feat, sc1, hb1, fb, n * CA);

  // conv1: out1 = subconv(h1, W1)  [N,128] fp32
  conv_k<CA, false><<<(n + 63) / 64, 256, 0, stream>>>(hb1, w1t, nbrt, nullptr, nullptr, out1, n);

  // stage 2
  col_stats_k<CB><<<256, 256, 0, stream>>>(out1, n, sums2);
  bn_finalize_k<CB><<<1, CB, 0, stream>>>(sums2, gamma2, beta2, sc2, n);
  bn_apply_k<CB, false><<<(n * CB / 4 + 255) / 256, 256, 0, stream>>>(out1, sc2, hb2, nullptr, n * CB);

  // conv2 + fused NiN shortcut
  conv_k<CB, true><<<(n + 63) / 64, 256, 0, stream>>>(hb2, w2t, nbrt, fb, wnt, out, n);
}